// Round 7
// baseline (474.083 us; speedup 1.0000x reference)
//
#include <hip/hip_runtime.h>
#include <hip/hip_bf16.h>

// SoftmaxSetAttention: out = softmax(Q K^T / sqrt(D) + log(mult)) V
// B=2 H=16 LQ=LK=2048 D=128, fp32 in/out, bf16 MFMA compute.
// Round 7: BN=32 tiles (40 KB LDS -> 4 blocks/CU) + split-K x2 (grid 1024 ->
// 4 waves/SIMD) + O^T PV operand swap (in-lane alpha/l, no bpermutes on the
// critical path). Partials: split0 -> d_out, split1 -> ws; merge kernel
// combines. Falls back to the proven round-6 path if ws_size is too small.
constexpr int B_  = 2;
constexpr int H_  = 16;
constexpr int LQ_ = 2048;
constexpr int LK_ = 2048;
constexpr int D_  = 128;

constexpr int BM = 128;                    // q rows per block (4 waves x 32)
constexpr float SCALE_LOG2E = 0.12751649734586414f;  // log2(e)/sqrt(128)

typedef short s16x4 __attribute__((ext_vector_type(4)));
typedef short s16x8 __attribute__((ext_vector_type(8)));
typedef float f32x4 __attribute__((ext_vector_type(4)));

#define MFMA16 __builtin_amdgcn_mfma_f32_16x16x32_bf16

#if __has_builtin(__builtin_amdgcn_exp2f)
#define EXP2(x) __builtin_amdgcn_exp2f(x)
#else
#define EXP2(x) exp2f(x)
#endif
#if __has_builtin(__builtin_amdgcn_logf)
#define LOG2(x) __builtin_amdgcn_logf(x)   // v_log_f32 computes log2
#else
#define LOG2(x) log2f(x)
#endif

static __device__ __forceinline__ int pk2bf(float a, float b) {
  float2 t{a, b};
  __hip_bfloat162 h = __float22bfloat162_rn(t);
  return *reinterpret_cast<int*>(&h);
}

static __device__ __forceinline__ void dma16(const short* g, short* l) {
  __builtin_amdgcn_global_load_lds(
      (const __attribute__((address_space(1))) void*)g,
      (__attribute__((address_space(3))) void*)l, 16, 0, 0);
}

// ============================ NEW PATH (BN=32, split-K x2) ==================
constexpr int TILE32 = 32 * 128;           // shorts per 8 KB sub-tile

// prep32: K -> bf16 sub-tiles (32 keys x 128 d, swizzle baked), V -> bf16
// transposed sub-tiles (128 d x 32 keys, swizzle baked), bias = log2(mult).
// wg = bh*32 + g64 handles a 64-key group -> two consecutive 8 KB sub-tiles.
__global__ __launch_bounds__(256)
void prep32(const float* __restrict__ kg, const float* __restrict__ vg,
            const int* __restrict__ multg, short* __restrict__ wsK,
            short* __restrict__ wsV, float* __restrict__ wsBias) {
  __shared__ float tileF[64 * 133];
  const int tid = threadIdx.x;
  const int wg  = blockIdx.x;                       // 0..1023
  const float* kp = kg + (size_t)wg * 64 * 128;
  const float* vp = vg + (size_t)wg * 64 * 128;
  short* wk = wsK + (size_t)wg * 2 * TILE32;
  short* wv = wsV + (size_t)wg * 2 * TILE32;

  // K convert: sub-tile layout row*128 + (blk^(row&15))*8
#pragma unroll
  for (int i = 0; i < 4; ++i) {
    int idx = tid + i * 256;                        // 0..1023
    int row = idx >> 4, blk = idx & 15;             // row=key 0..63
    const float* src = kp + row * 128 + blk * 8;
    float4 a = *(const float4*)src;
    float4 c4 = *(const float4*)(src + 4);
    int4 t;
    t.x = pk2bf(a.x, a.y);  t.y = pk2bf(a.z, a.w);
    t.z = pk2bf(c4.x, c4.y); t.w = pk2bf(c4.z, c4.w);
    int pos = blk ^ (row & 15);
    *(int4*)&wk[(row >> 5) * TILE32 + (row & 31) * 128 + pos * 8] = t;
  }

  // V transpose through LDS
#pragma unroll
  for (int i = 0; i < 8; ++i) {
    int idx = tid + i * 256;                        // 0..2047
    int key = idx >> 5, d0 = (idx & 31) * 4;
    float4 a = *(const float4*)(vp + key * 128 + d0);
    float* dst = &tileF[key * 133 + d0];
    dst[0] = a.x; dst[1] = a.y; dst[2] = a.z; dst[3] = a.w;
  }
  __syncthreads();
  // V^T sub-tile layout: d*32 + ((kg2)^((d>>1)&3))*8, kg2 = key-block in sub-tile
#pragma unroll
  for (int i = 0; i < 4; ++i) {
    int idx = tid + i * 256;                        // 0..1023
    int d = idx >> 3, kgrp = idx & 7;               // kgrp = 8-key group 0..7
    float v[8];
#pragma unroll
    for (int j = 0; j < 8; ++j) v[j] = tileF[(kgrp * 8 + j) * 133 + d];
    int4 t;
    t.x = pk2bf(v[0], v[1]); t.y = pk2bf(v[2], v[3]);
    t.z = pk2bf(v[4], v[5]); t.w = pk2bf(v[6], v[7]);
    int pos = (kgrp & 3) ^ ((d >> 1) & 3);
    *(int4*)&wv[(kgrp >> 2) * TILE32 + d * 32 + pos * 8] = t;
  }

  // bias
  if (wg < 8) {
    int b = wg >> 2;
    for (int j = tid; j < 512; j += 256) {
      int i0 = (wg & 3) * 512 + j;
      wsBias[b * LK_ + i0] = LOG2((float)multg[b * LK_ + i0]);
    }
  }
}

__global__ __launch_bounds__(256, 4)
void attn32(const float* __restrict__ qg, const short* __restrict__ wsK,
            const short* __restrict__ wsV, const float* __restrict__ wsBias,
            float* __restrict__ outg, float* __restrict__ part1,
            float2* __restrict__ wsML) {
  __shared__ alignas(16) short Kbuf[2][TILE32];   // 2 x 8 KB
  __shared__ alignas(16) short Vbuf[2][TILE32];   // 2 x 8 KB
  __shared__ alignas(16) short Psh[128 * 32];     // 8 KB -> 40 KB total

  const int tid  = threadIdx.x;
  const int w    = tid >> 6;
  const int lane = tid & 63;
  const int c    = lane & 15;
  const int qd   = lane >> 4;

  // XCD swizzle: L%8 = XCD; each XCD owns 4 bh; per bh: 16 qb x 2 splits.
  const int L   = blockIdx.x;            // 0..1023
  const int xcd = L & 7;
  const int idx = L >> 3;                // 0..127
  const int bh  = xcd * 4 + (idx >> 5);
  const int rem = idx & 31;
  const int qb  = rem & 15;
  const int s   = rem >> 4;              // split 0/1
  const int b   = bh >> 4;

  const float* qptr = qg + (size_t)bh * LQ_ * D_;
  float* obase = (s ? part1 : outg) + (size_t)bh * LQ_ * D_;
  const short* kws = wsK + ((size_t)bh * 64 + s * 32) * TILE32;
  const short* vws = wsV + ((size_t)bh * 64 + s * 32) * TILE32;
  const float* bias = wsBias + b * LK_ + s * 1024;
  float2* mlp = wsML + (size_t)s * 32 * LQ_ + (size_t)bh * LQ_;

  // Q fragments (B-operand: n=q-row=c, k=qd*8+j+32kf), scale folded in
  const int q0 = qb * BM + w * 32;
  s16x8 qf[2][4];
#pragma unroll
  for (int qs = 0; qs < 2; ++qs) {
    const float* qrow = qptr + (size_t)(q0 + qs * 16 + c) * D_ + qd * 8;
#pragma unroll
    for (int kf = 0; kf < 4; ++kf) {
      float4 a  = *(const float4*)(qrow + kf * 32);
      float4 bq = *(const float4*)(qrow + kf * 32 + 4);
      int4 t;
      t.x = pk2bf(a.x * SCALE_LOG2E, a.y * SCALE_LOG2E);
      t.y = pk2bf(a.z * SCALE_LOG2E, a.w * SCALE_LOG2E);
      t.z = pk2bf(bq.x * SCALE_LOG2E, bq.y * SCALE_LOG2E);
      t.w = pk2bf(bq.z * SCALE_LOG2E, bq.w * SCALE_LOG2E);
      qf[qs][kf] = *(s16x8*)&t;
    }
  }

  // O^T accumulators: o[qs][dt][reg] = O^T[d=dt*16+qd*4+reg][q = q0+qs*16+c]
  f32x4 o[2][8];
  float m_r[2], l_r[2];
#pragma unroll
  for (int qs = 0; qs < 2; ++qs) {
#pragma unroll
    for (int dt = 0; dt < 8; ++dt) o[qs][dt] = (f32x4){0.f, 0.f, 0.f, 0.f};
    m_r[qs] = -INFINITY; l_r[qs] = 0.f;
  }

  auto dmaKV = [&](int kt, int bb) {
    const short* gK = kws + (size_t)kt * TILE32;
    const short* gV = vws + (size_t)kt * TILE32;
#pragma unroll
    for (int i = 0; i < 2; ++i) {
      int off = (w * 2 + i) * 512;
      dma16(gK + off + lane * 8, &Kbuf[bb][off]);
      dma16(gV + off + lane * 8, &Vbuf[bb][off]);
    }
  };

  dmaKV(0, 0);
  __syncthreads();

  for (int kt = 0; kt < 32; ++kt) {
    const int cur = kt & 1;
    if (kt + 1 < 32) dmaKV(kt + 1, cur ^ 1);

    float bvf[2][4];
#pragma unroll
    for (int ct = 0; ct < 2; ++ct) {
      float4 bv = *(const float4*)&bias[kt * 32 + ct * 16 + qd * 4];
      bvf[ct][0] = bv.x; bvf[ct][1] = bv.y; bvf[ct][2] = bv.z; bvf[ct][3] = bv.w;
    }

    // S^T = K Q^T : lane holds keys {ct*16+qd*4+reg} for q-row c
    f32x4 St[2][2];
#pragma unroll
    for (int qs = 0; qs < 2; ++qs)
#pragma unroll
      for (int ct = 0; ct < 2; ++ct) St[qs][ct] = (f32x4){0.f, 0.f, 0.f, 0.f};

#pragma unroll
    for (int ct = 0; ct < 2; ++ct) {
      const short* kb = &Kbuf[cur][(ct * 16 + c) * 128];
#pragma unroll
      for (int kf = 0; kf < 4; ++kf) {
        s16x8 kfr = *(const s16x8*)&kb[((kf * 4 + qd) ^ c) * 8];
        St[0][ct] = MFMA16(kfr, qf[0][kf], St[0][ct], 0, 0, 0);
        St[1][ct] = MFMA16(kfr, qf[1][kf], St[1][ct], 0, 0, 0);
      }
    }

    // online softmax (in-lane + 2 bpermutes for max; sum shuffles off-path)
#pragma unroll
    for (int qs = 0; qs < 2; ++qs) {
      float x[2][4];
#pragma unroll
      for (int ct = 0; ct < 2; ++ct)
#pragma unroll
        for (int reg = 0; reg < 4; ++reg)
          x[ct][reg] = St[qs][ct][reg] + bvf[ct][reg];

      float mx = x[0][0];
#pragma unroll
      for (int ct = 0; ct < 2; ++ct)
#pragma unroll
        for (int reg = 0; reg < 4; ++reg) mx = fmaxf(mx, x[ct][reg]);
      mx = fmaxf(mx, __shfl_xor(mx, 16));
      mx = fmaxf(mx, __shfl_xor(mx, 32));

      float mn    = fmaxf(m_r[qs], mx);
      float alpha = EXP2(m_r[qs] - mn);
      m_r[qs] = mn;

      float rs = 0.f;
#pragma unroll
      for (int ct = 0; ct < 2; ++ct)
#pragma unroll
        for (int reg = 0; reg < 4; ++reg) {
          float p = EXP2(x[ct][reg] - mn);
          x[ct][reg] = p;
          rs += p;
        }
      rs += __shfl_xor(rs, 16);
      rs += __shfl_xor(rs, 32);
      l_r[qs] = l_r[qs] * alpha + rs;

      // P write: row pr, keys ct*16+qd*4+{0..3}; 4 x 16B blocks, XOR (pr&3)
      const int pr = w * 32 + qs * 16 + c;
#pragma unroll
      for (int ct = 0; ct < 2; ++ct) {
        int2 pk;
        pk.x = pk2bf(x[ct][0], x[ct][1]);
        pk.y = pk2bf(x[ct][2], x[ct][3]);
        int pos = (ct * 2 + (qd >> 1)) ^ (pr & 3);
        *(int2*)&Psh[pr * 32 + pos * 8 + (qd & 1) * 4] = pk;
      }

      // O^T rescale: column q=c -> in-lane scalar alpha
#pragma unroll
      for (int dt = 0; dt < 8; ++dt)
#pragma unroll
        for (int reg = 0; reg < 4; ++reg) o[qs][dt][reg] *= alpha;
    }

    // O^T += V^T P^T (operand-swapped MFMA)
    s16x8 pf[2];
#pragma unroll
    for (int qs = 0; qs < 2; ++qs) {
      const int pr = w * 32 + qs * 16 + c;
      pf[qs] = *(const s16x8*)&Psh[pr * 32 + (qd ^ (pr & 3)) * 8];
    }
#pragma unroll
    for (int dt = 0; dt < 8; ++dt) {
      int d = dt * 16 + c;
      s16x8 vf = *(const s16x8*)&Vbuf[cur][d * 32 + (qd ^ ((d >> 1) & 3)) * 8];
      o[0][dt] = MFMA16(vf, pf[0], o[0][dt], 0, 0, 0);
      o[1][dt] = MFMA16(vf, pf[1], o[1][dt], 0, 0, 0);
    }

    __syncthreads();
  }

  // epilogue: store UN-normalized partial O^T (as float4 per lane) + (m,l)
#pragma unroll
  for (int qs = 0; qs < 2; ++qs) {
    float* orow = obase + (size_t)(q0 + qs * 16 + c) * D_ + qd * 4;
#pragma unroll
    for (int dt = 0; dt < 8; ++dt)
      *(f32x4*)(orow + dt * 16) = o[qs][dt];
    if (qd == 0)
      mlp[q0 + qs * 16 + c] = make_float2(m_r[qs], l_r[qs]);
  }
}

__global__ __launch_bounds__(256)
void merge(float4* __restrict__ out, const float4* __restrict__ p1,
           const float2* __restrict__ ml0, const float2* __restrict__ ml1) {
  int gid = blockIdx.x * 256 + threadIdx.x;       // one float4 each
  int row = gid >> 5;                             // bh*2048 + q
  float2 a = ml0[row], bb = ml1[row];
  float m = fmaxf(a.x, bb.x);
  float s0 = EXP2(a.x - m), s1 = EXP2(bb.x - m);
  float inv = 1.0f / (a.y * s0 + bb.y * s1);
  float4 o0 = out[gid], o1 = p1[gid];
  float4 r;
  r.x = (o0.x * s0 + o1.x * s1) * inv;
  r.y = (o0.y * s0 + o1.y * s1) * inv;
  r.z = (o0.z * s0 + o1.z * s1) * inv;
  r.w = (o0.w * s0 + o1.w * s1) * inv;
  out[gid] = r;
}

// ===================== FALLBACK PATH (round-6, proven) ======================
constexpr int NT64 = 32;
constexpr int TILE64 = 64 * 128;

__global__ __launch_bounds__(256)
void prep64(const float* __restrict__ kg, const float* __restrict__ vg,
            const int* __restrict__ multg, short* __restrict__ wsK,
            short* __restrict__ wsV, float* __restrict__ wsBias) {
  __shared__ float tileF[64 * 133];
  const int tid = threadIdx.x;
  const int wg  = blockIdx.x;
  const float* kp = kg + (size_t)wg * 64 * 128;
  const float* vp = vg + (size_t)wg * 64 * 128;
  short* wk = wsK + (size_t)wg * TILE64;
  short* wv = wsV + (size_t)wg * TILE64;

#pragma unroll
  for (int i = 0; i < 4; ++i) {
    int idx = tid + i * 256;
    int row = idx >> 4, blk = idx & 15;
    const float* src = kp + row * 128 + blk * 8;
    float4 a = *(const float4*)src;
    float4 c4 = *(const float4*)(src + 4);
    int4 t;
    t.x = pk2bf(a.x, a.y);  t.y = pk2bf(a.z, a.w);
    t.z = pk2bf(c4.x, c4.y); t.w = pk2bf(c4.z, c4.w);
    int pos = blk ^ (row & 15);
    *(int4*)&wk[row * 128 + pos * 8] = t;
  }
#pragma unroll
  for (int i = 0; i < 8; ++i) {
    int idx = tid + i * 256;
    int key = idx >> 5, d0 = (idx & 31) * 4;
    float4 a = *(const float4*)(vp + key * 128 + d0);
    float* dst = &tileF[key * 133 + d0];
    dst[0] = a.x; dst[1] = a.y; dst[2] = a.z; dst[3] = a.w;
  }
  __syncthreads();
#pragma unroll
  for (int i = 0; i < 4; ++i) {
    int idx = tid + i * 256;
    int d = idx >> 3, kgrp = idx & 7;
    float v[8];
#pragma unroll
    for (int j = 0; j < 8; ++j) v[j] = tileF[(kgrp * 8 + j) * 133 + d];
    int4 t;
    t.x = pk2bf(v[0], v[1]); t.y = pk2bf(v[2], v[3]);
    t.z = pk2bf(v[4], v[5]); t.w = pk2bf(v[6], v[7]);
    int pos = kgrp ^ ((d >> 1) & 7);
    *(int4*)&wv[d * 64 + pos * 8] = t;
  }
  if (wg < 8) {
    int b = wg >> 2;
    for (int j = tid; j < 512; j += 256) {
      int i0 = (wg & 3) * 512 + j;
      wsBias[b * LK_ + i0] = LOG2((float)multg[b * LK_ + i0]);
    }
  }
}

__global__ __launch_bounds__(256, 2)
void attn64(const float* __restrict__ qg, const short* __restrict__ wsK,
            const short* __restrict__ wsV, const float* __restrict__ wsBias,
            float* __restrict__ outg) {
  __shared__ alignas(16) short Kbuf[2][TILE64];
  __shared__ alignas(16) short Vbuf[2][TILE64];
  __shared__ alignas(16) short Psh[128 * 64];

  const int tid  = threadIdx.x;
  const int w    = tid >> 6;
  const int lane = tid & 63;
  const int c    = lane & 15;
  const int qd   = lane >> 4;

  const int L   = blockIdx.y * gridDim.x + blockIdx.x;
  const int k8  = L >> 3;
  const int qb  = k8 & 15;
  const int bh  = (L & 7) * 4 + (k8 >> 4);
  const int b   = bh >> 4;

  const float* qptr = qg + (size_t)bh * LQ_ * D_;
  float*       optr = outg + (size_t)bh * LQ_ * D_;
  const short* kws  = wsK + (size_t)bh * NT64 * TILE64;
  const short* vws  = wsV + (size_t)bh * NT64 * TILE64;
  const float* bias = wsBias + b * LK_;

  const int q0 = qb * BM + w * 32;
  s16x8 qf[2][4];
#pragma unroll
  for (int qs = 0; qs < 2; ++qs) {
    const float* qrow = qptr + (size_t)(q0 + qs * 16 + c) * D_ + qd * 8;
#pragma unroll
    for (int kf = 0; kf < 4; ++kf) {
      float4 a  = *(const float4*)(qrow + kf * 32);
      float4 bq = *(const float4*)(qrow + kf * 32 + 4);
      int4 t;
      t.x = pk2bf(a.x * SCALE_LOG2E, a.y * SCALE_LOG2E);
      t.y = pk2bf(a.z * SCALE_LOG2E, a.w * SCALE_LOG2E);
      t.z = pk2bf(bq.x * SCALE_LOG2E, bq.y * SCALE_LOG2E);
      t.w = pk2bf(bq.z * SCALE_LOG2E, bq.w * SCALE_LOG2E);
      qf[qs][kf] = *(s16x8*)&t;
    }
  }

  f32x4 o[2][8];
  float m_r[2], l_r[2];
#pragma unroll
  for (int qs = 0; qs < 2; ++qs) {
#pragma unroll
    for (int dt = 0; dt < 8; ++dt) o[qs][dt] = (f32x4){0.f, 0.f, 0.f, 0.f};
    m_r[qs] = -INFINITY; l_r[qs] = 0.f;
  }

  auto dmaKV = [&](int kt, int bb) {
    const short* gK = kws + (size_t)kt * TILE64;
    const short* gV = vws + (size_t)kt * TILE64;
#pragma unroll
    for (int i = 0; i < 4; ++i) {
      int off = (w * 4 + i) * 512;
      dma16(gK + off + lane * 8, &Kbuf[bb][off]);
      dma16(gV + off + lane * 8, &Vbuf[bb][off]);
    }
  };

  dmaKV(0, 0);
  __syncthreads();

  for (int kt = 0; kt < NT64; ++kt) {
    const int cur = kt & 1;
    if (kt + 1 < NT64) dmaKV(kt + 1, cur ^ 1);

    float bvf[4][4];
#pragma unroll
    for (int ct = 0; ct < 4; ++ct) {
      float4 bv = *(const float4*)&bias[kt * 64 + ct * 16 + qd * 4];
      bvf[ct][0] = bv.x; bvf[ct][1] = bv.y; bvf[ct][2] = bv.z; bvf[ct][3] = bv.w;
    }

    f32x4 St[2][4];
#pragma unroll
    for (int qs = 0; qs < 2; ++qs)
#pragma unroll
      for (int ct = 0; ct < 4; ++ct) St[qs][ct] = (f32x4){0.f, 0.f, 0.f, 0.f};

#pragma unroll
    for (int ct = 0; ct < 4; ++ct) {
      const short* kb = &Kbuf[cur][(ct * 16 + c) * 128];
#pragma unroll
      for (int kf = 0; kf < 4; ++kf) {
        s16x8 kfr = *(const s16x8*)&kb[((kf * 4 + qd) ^ c) * 8];
        St[0][ct] = MFMA16(kfr, qf[0][kf], St[0][ct], 0, 0, 0);
        St[1][ct] = MFMA16(kfr, qf[1][kf], St[1][ct], 0, 0, 0);
      }
    }

#pragma unroll
    for (int qs = 0; qs < 2; ++qs) {
      float x[4][4];
#pragma unroll
      for (int ct = 0; ct < 4; ++ct)
#pragma unroll
        for (int reg = 0; reg < 4; ++reg)
          x[ct][reg] = St[qs][ct][reg] + bvf[ct][reg];

      float mx = x[0][0];
#pragma unroll
      for (int ct = 0; ct < 4; ++ct)
#pragma unroll
        for (int reg = 0; reg < 4; ++reg) mx = fmaxf(mx, x[ct][reg]);
      mx = fmaxf(mx, __shfl_xor(mx, 16));
      mx = fmaxf(mx, __shfl_xor(mx, 32));

      float mn    = fmaxf(m_r[qs], mx);
      float alpha = EXP2(m_r[qs] - mn);
      m_r[qs] = mn;

      float rs = 0.f;
#pragma unroll
      for (int ct = 0; ct < 4; ++ct)
#pragma unroll
        for (int reg = 0; reg < 4; ++reg) {
          float p = EXP2(x[ct][reg] - mn);
          x[ct][reg] = p;
          rs += p;
        }
      rs += __shfl_xor(rs, 16);
      rs += __shfl_xor(rs, 32);
      l_r[qs] = l_r[qs] * alpha + rs;

      const int pr = w * 32 + qs * 16 + c;
#pragma unroll
      for (int ct = 0; ct < 4; ++ct) {
        int2 pk;
        pk.x = pk2bf(x[ct][0], x[ct][1]);
        pk.y = pk2bf(x[ct][2], x[ct][3]);
        int pos = (ct * 2 + (qd >> 1)) ^ (pr & 7);
        *(int2*)&Psh[pr * 64 + pos * 8 + (qd & 1) * 4] = pk;
      }

      float ar[4];
#pragma unroll
      for (int reg = 0; reg < 4; ++reg) ar[reg] = __shfl(alpha, qd * 4 + reg);
#pragma unroll
      for (int dt = 0; dt < 8; ++dt)
#pragma unroll
        for (int reg = 0; reg < 4; ++reg) o[qs][dt][reg] *= ar[reg];
    }

    s16x8 pf[2][2];
#pragma unroll
    for (int qs = 0; qs < 2; ++qs) {
      const int pr = w * 32 + qs * 16 + c;
#pragma unroll
      for (int kf = 0; kf < 2; ++kf) {
        int pos = (kf * 4 + qd) ^ (pr & 7);
        pf[qs][kf] = *(const s16x8*)&Psh[pr * 64 + pos * 8];
      }
    }
#pragma unroll
    for (int dt = 0; dt < 8; ++dt) {
      int d = dt * 16 + c;
      const short* vb = &Vbuf[cur][d * 64];
      s16x8 vf[2];
#pragma unroll
      for (int kf = 0; kf < 2; ++kf)
        vf[kf] = *(const s16x8*)&vb[((kf * 4 + qd) ^ ((d >> 1) & 7)) * 8];
#pragma unroll
      for (int qs = 0; qs < 2; ++qs)
#pragma unroll
        for (int kf = 0; kf < 2; ++kf)
          o[qs][dt] = MFMA16(pf[qs][kf], vf[kf], o[qs][dt], 0, 0, 0);
    }

    __syncthreads();
  }

#pragma unroll
  for (int qs = 0; qs < 2; ++qs) {
    float lr[4];
#pragma unroll
    for (int reg = 0; reg < 4; ++reg) lr[reg] = __shfl(l_r[qs], qd * 4 + reg);
#pragma unroll
    for (int reg = 0; reg < 4; ++reg) {
      float inv = 1.0f / lr[reg];
      int row = q0 + qs * 16 + qd * 4 + reg;
      float* orow = optr + (size_t)row * D_ + c;
#pragma unroll
      for (int dt = 0; dt < 8; ++dt) orow[dt * 16] = o[qs][dt][reg] * inv;
    }
  }
}

// ============================ launcher ======================================
extern "C" void kernel_launch(void* const* d_in, const int* in_sizes, int n_in,
                              void* d_out, int out_size, void* d_ws, size_t ws_size,
                              hipStream_t stream) {
  const float* q = (const float*)d_in[0];
  const float* k = (const float*)d_in[1];
  const float* v = (const float*)d_in[2];
  const int* mult = (const int*)d_in[3];
  float* out = (float*)d_out;

  constexpr size_t KV_BYTES  = (size_t)B_ * H_ * LK_ * D_ * 2;   // 16 MB each
  constexpr size_t O_BYTES   = (size_t)B_ * H_ * LQ_ * D_ * 4;   // 32 MB
  constexpr size_t ML_BYTES  = (size_t)2 * B_ * H_ * LQ_ * 8;    // 1 MB
  constexpr size_t NEED_NEW  = 2 * KV_BYTES + O_BYTES + ML_BYTES + LK_ * B_ * 4;

  if (ws_size >= NEED_NEW) {
    short*  wsK    = (short*)d_ws;
    short*  wsV    = (short*)((char*)d_ws + KV_BYTES);
    float*  part1  = (float*)((char*)d_ws + 2 * KV_BYTES);
    float2* wsML   = (float2*)((char*)d_ws + 2 * KV_BYTES + O_BYTES);
    float*  wsBias = (float*)((char*)d_ws + 2 * KV_BYTES + O_BYTES + ML_BYTES);
    const float2* ml0 = wsML;
    const float2* ml1 = wsML + (size_t)B_ * H_ * LQ_;

    prep32<<<dim3(B_ * H_ * 32), dim3(256), 0, stream>>>(k, v, mult, wsK, wsV, wsBias);
    attn32<<<dim3(1024), dim3(256), 0, stream>>>(q, wsK, wsV, wsBias, out, part1, wsML);
    merge<<<dim3((B_ * H_ * LQ_ * D_ / 4) / 256), dim3(256), 0, stream>>>(
        (float4*)out, (const float4*)part1, ml0, ml1);
  } else {
    short* wsK = (short*)d_ws;
    short* wsV = (short*)((char*)d_ws + KV_BYTES);
    float* wsBias = (float*)((char*)d_ws + 2 * KV_BYTES);
    prep64<<<dim3(B_ * H_ * NT64), dim3(256), 0, stream>>>(k, v, mult, wsK, wsV, wsBias);
    dim3 grid(LQ_ / BM, B_ * H_);
    attn64<<<grid, dim3(256), 0, stream>>>(q, wsK, wsV, wsBias, out);
  }
}